// Round 4
// baseline (254.054 us; speedup 1.0000x reference)
//
#include <hip/hip_runtime.h>
#include <hip/hip_bf16.h>

// ModuleCorrelation as implicit GEMM on MFMA (bf16 in, fp32 acc), v4.
// out[b, dy*9+dx, y, x] = (1/64) sum_c F[b,c,y,x] * S[b,c,y+dy-4,x+dx-4]
//
// v4 changes vs v3:
//  - dy-split: wave = (b, y, dy-group of 3, 16-px x-tile). acc shrinks
//    144 -> 24 floats => ~4 waves/SIMD and 46,080 waves (latency hiding).
//  - prepass fused into ONE kernel (pad borders written in-kernel; no
//    fill_zero): F fp32 CHW -> bf16 HWC (Fc), S fp32 CHW -> bf16 padded
//    (H+8)(W+8)C (Sp).
//  - epilogue: write C-layout natural to per-wave LDS (stride 25), read
//    banded (26m+dx: uniform 2-way, free), stores 64B-contiguous.

#define WW   320
#define HH   192
#define CC   64
#define HWSZ (HH * WW)
#define NB   4
#define PW   328   // WW + 8
#define PH   200   // HH + 8
#define NDISP 81

typedef __attribute__((ext_vector_type(8))) short bf16x8_t;   // 8 bf16 (4 VGPRs)
typedef __attribute__((ext_vector_type(4))) float f32x4_t;    // 4 fp32

static __device__ __forceinline__ unsigned short f2bf(float f) {
    unsigned int u = __float_as_uint(f);
    u += 0x7fffu + ((u >> 16) & 1u);   // round-nearest-even
    return (unsigned short)(u >> 16);
}

// ---------------- kernel 1: fused prepass ----------------
// z = blockIdx.z: b = z&3, isS = z>>2.
//  F path: [C][H][W] fp32 -> Fc [H][W][C] bf16            (bx 0..4, y 0..191)
//  S path: [C][H][W] fp32 -> Sp [PH][PW][C] bf16, +4 pad  (bx 0..5, py 0..199)
__global__ __launch_bounds__(256)
void prep(const float* __restrict__ F, const float* __restrict__ S,
          unsigned short* __restrict__ Fc, unsigned short* __restrict__ Sp) {
    const int b   = blockIdx.z & 3;
    const int isS = blockIdx.z >> 2;
    const int tx = threadIdx.x;      // 0..63
    const int ty = threadIdx.y;      // 0..3

    __shared__ float tile[64][65];   // [c][x]

    if (!isS) {
        // ----- F -> Fc -----
        const int x0 = blockIdx.x * 64;
        const int y  = blockIdx.y;
        if (x0 >= WW || y >= HH) return;           // block-uniform exit
        const float* src = F + (size_t)b * CC * HWSZ + (size_t)y * WW + x0 + tx;
#pragma unroll
        for (int i = 0; i < 16; ++i) {
            int c = ty * 16 + i;
            tile[c][tx] = src[(size_t)c * HWSZ];
        }
        __syncthreads();
        const int t  = ty * 64 + tx;
        const int xx = t >> 2;
        const int cg = (t & 3) * 16;
        unsigned short tmp[16];
#pragma unroll
        for (int i = 0; i < 16; ++i) tmp[i] = f2bf(tile[cg + i][xx]);
        unsigned short* dst = Fc + (((size_t)b * HH + y) * WW + (x0 + xx)) * CC + cg;
        uint4 v;
        v.x = (unsigned)tmp[0]  | ((unsigned)tmp[1]  << 16);
        v.y = (unsigned)tmp[2]  | ((unsigned)tmp[3]  << 16);
        v.z = (unsigned)tmp[4]  | ((unsigned)tmp[5]  << 16);
        v.w = (unsigned)tmp[6]  | ((unsigned)tmp[7]  << 16);
        *(uint4*)dst = v;
        v.x = (unsigned)tmp[8]  | ((unsigned)tmp[9]  << 16);
        v.y = (unsigned)tmp[10] | ((unsigned)tmp[11] << 16);
        v.z = (unsigned)tmp[12] | ((unsigned)tmp[13] << 16);
        v.w = (unsigned)tmp[14] | ((unsigned)tmp[15] << 16);
        *(uint4*)(dst + 8) = v;
    } else {
        // ----- S -> Sp (padded; zeros written for out-of-range) -----
        const int px0 = blockIdx.x * 64;           // padded x base, 0..383
        const int py  = blockIdx.y;                // padded y, 0..199
        if (px0 >= PW) return;
        const int gy = py - 4;
        const int gx = px0 - 4 + tx;
        float val = 0.f;
        if ((unsigned)gy < (unsigned)HH && (unsigned)gx < (unsigned)WW) {
            const float* src = S + (size_t)b * CC * HWSZ + (size_t)gy * WW + gx;
#pragma unroll
            for (int i = 0; i < 16; ++i) {
                int c = ty * 16 + i;
                tile[c][tx] = src[(size_t)c * HWSZ];
            }
        } else {
#pragma unroll
            for (int i = 0; i < 16; ++i) tile[ty * 16 + i][tx] = 0.f;
        }
        // NOTE: rows with gy valid but some gx invalid: handle per-element
        if ((unsigned)gy < (unsigned)HH && !((unsigned)gx < (unsigned)WW)) {
#pragma unroll
            for (int i = 0; i < 16; ++i) tile[ty * 16 + i][tx] = 0.f;
        }
        __syncthreads();
        const int t  = ty * 64 + tx;
        const int xx = t >> 2;
        const int cg = (t & 3) * 16;
        const int px = px0 + xx;
        if (px < PW) {
            unsigned short tmp[16];
#pragma unroll
            for (int i = 0; i < 16; ++i) tmp[i] = f2bf(tile[cg + i][xx]);
            unsigned short* dst = Sp + (((size_t)b * PH + py) * PW + px) * CC + cg;
            uint4 v;
            v.x = (unsigned)tmp[0]  | ((unsigned)tmp[1]  << 16);
            v.y = (unsigned)tmp[2]  | ((unsigned)tmp[3]  << 16);
            v.z = (unsigned)tmp[4]  | ((unsigned)tmp[5]  << 16);
            v.w = (unsigned)tmp[6]  | ((unsigned)tmp[7]  << 16);
            *(uint4*)dst = v;
            v.x = (unsigned)tmp[8]  | ((unsigned)tmp[9]  << 16);
            v.y = (unsigned)tmp[10] | ((unsigned)tmp[11] << 16);
            v.z = (unsigned)tmp[12] | ((unsigned)tmp[13] << 16);
            v.w = (unsigned)tmp[14] | ((unsigned)tmp[15] << 16);
            *(uint4*)(dst + 8) = v;
        }
    }
}

// ---------------- kernel 2: MFMA correlation, dy-split ----------------
// wave = (b, y, dy-group of 3, 16-px x-tile); 46,080 waves in 11,520 blocks.
// XCD slab: blockIdx%8 -> fixed 24-row y-slab; block's 4 waves = adjacent
// x-tiles (L1 window overlap).
__global__ __launch_bounds__(256, 4)
void corr_mfma_v4(const unsigned short* __restrict__ Fc,
                  const unsigned short* __restrict__ Sp,
                  float* __restrict__ out) {
    __shared__ float ebuf[4][3 * 16 * 25];   // per-wave [r][m][n(24)+pad], 19.2 KB

    const int tid  = threadIdx.x;
    const int wave = tid >> 6;
    const int lane = tid & 63;
    const int q    = lane >> 4;
    const int col  = lane & 15;

    const int xcd = blockIdx.x & 7;
    const int k   = (blockIdx.x >> 3) * 4 + wave;   // 0..5759 per XCD
    const int xt  = k % 20;
    const int dyg = (k / 20) % 3;
    const int yl  = (k / 60) % 24;
    const int b   = k / 1440;
    const int y   = xcd * 24 + yl;
    const int x0  = xt * 16;

    // ---- A fragments: per-lane contiguous b128 from channels-last Fc
    const unsigned short* fc =
        Fc + (((size_t)b * HH + y) * WW + (x0 + col)) * CC + q * 8;
    const bf16x8_t a0 = *(const bf16x8_t*)(fc);         // k 0..31
    const bf16x8_t a1 = *(const bf16x8_t*)(fc + 32);    // k 32..63

    // ---- B loads: 3 rows x 2 n-tiles x 2 k-slices, all independent
    const int xp0 = x0 + col;
    int xp1 = x0 + col + 16;
    xp1 = xp1 > (PW - 1) ? (PW - 1) : xp1;   // clamped lanes never enter the band
    bf16x8_t bb[3][2][2];
#pragma unroll
    for (int r = 0; r < 3; ++r) {
        const unsigned short* srow =
            Sp + ((size_t)b * PH + (y + 3 * dyg + r)) * PW * CC;
        const unsigned short* p0 = srow + (size_t)xp0 * CC + q * 8;
        const unsigned short* p1 = srow + (size_t)xp1 * CC + q * 8;
        bb[r][0][0] = *(const bf16x8_t*)(p0);
        bb[r][0][1] = *(const bf16x8_t*)(p0 + 32);
        bb[r][1][0] = *(const bf16x8_t*)(p1);
        bb[r][1][1] = *(const bf16x8_t*)(p1 + 32);
    }

    f32x4_t acc[3][2];
#pragma unroll
    for (int r = 0; r < 3; ++r)
#pragma unroll
        for (int nt = 0; nt < 2; ++nt)
#pragma unroll
            for (int kk = 0; kk < 4; ++kk) acc[r][nt][kk] = 0.f;

#pragma unroll
    for (int r = 0; r < 3; ++r)
#pragma unroll
        for (int nt = 0; nt < 2; ++nt) {
            acc[r][nt] = __builtin_amdgcn_mfma_f32_16x16x32_bf16(a0, bb[r][nt][0], acc[r][nt], 0, 0, 0);
            acc[r][nt] = __builtin_amdgcn_mfma_f32_16x16x32_bf16(a1, bb[r][nt][1], acc[r][nt], 0, 0, 0);
        }

    // ---- epilogue: C-layout natural write to per-wave LDS (stride 25)
    const float scale = 1.0f / 64.0f;
    float* my = ebuf[wave];
#pragma unroll
    for (int r = 0; r < 3; ++r)
#pragma unroll
        for (int nt = 0; nt < 2; ++nt)
#pragma unroll
            for (int kk = 0; kk < 4; ++kk) {
                int m = 4 * q + kk;
                int n = col + 16 * nt;
                if (n < 24)
                    my[r * 400 + m * 25 + n] = acc[r][nt][kk] * scale;
            }
    // in-wave lgkmcnt ordering suffices (per-wave staging; verified in v3)

    // ---- banded reads + 64B-contiguous stores
    // ld = 4*rnd + q (local plane index r*9+dx), m = col
    float* ob = out + ((size_t)b * NDISP + 27 * dyg) * HWSZ + (size_t)y * WW + x0;
#pragma unroll
    for (int rnd = 0; rnd < 7; ++rnd) {
        const int ld = 4 * rnd + q;
        if (ld < 27) {
            const int r  = ld / 9;
            const int dx = ld - 9 * r;
            const float v = my[r * 400 + 26 * col + dx];   // m*25 + (m+dx), m=col
            ob[(size_t)ld * HWSZ + col] = v;
        }
    }
}

// ---------------- last-resort fallback: direct fp32 kernel ----------------
#define MDV      4
#define TILE_X   64
#define TILE_Y   8
#define CH_STAGE 4
#define LDS_ROWS (TILE_Y + 2 * MDV)
#define LDS_COLS (TILE_X + 2 * MDV)

__global__ __launch_bounds__(256, 2)
void corr_direct(const float* __restrict__ first,
                 const float* __restrict__ second,
                 float* __restrict__ out) {
    const int C = 64, H = HH, W = WW;
    const int HW = H * W;
    __shared__ float lds[CH_STAGE][LDS_ROWS * LDS_COLS];
    const int tx = threadIdx.x, ty = threadIdx.y;
    const int tid = ty * 32 + tx;
    const int x_tile = blockIdx.x * TILE_X;
    const int y_tile = blockIdx.y * TILE_Y;
    const int b = blockIdx.z;
    const int x0 = x_tile + 2 * tx;
    const int y  = y_tile + ty;
    const float* fst_b = first  + (size_t)b * C * HW;
    const float* sec_b = second + (size_t)b * C * HW;
    float acc[NDISP][2];
#pragma unroll
    for (int d = 0; d < NDISP; ++d) { acc[d][0] = 0.f; acc[d][1] = 0.f; }
    for (int cb = 0; cb < C; cb += CH_STAGE) {
        __syncthreads();
        const int total = CH_STAGE * LDS_ROWS * LDS_COLS;
#pragma unroll
        for (int kk = 0; kk < total / 256; ++kk) {
            int i = tid + kk * 256;
            int c   = i / (LDS_ROWS * LDS_COLS);
            int rem = i - c * (LDS_ROWS * LDS_COLS);
            int r   = rem / LDS_COLS;
            int cl  = rem - r * LDS_COLS;
            int gy = y_tile - MDV + r;
            int gx = x_tile - MDV + cl;
            float v = 0.f;
            if ((unsigned)gy < (unsigned)H && (unsigned)gx < (unsigned)W)
                v = sec_b[(size_t)(cb + c) * HW + gy * W + gx];
            lds[c][rem] = v;
        }
        __syncthreads();
#pragma unroll
        for (int cl = 0; cl < CH_STAGE; ++cl) {
            const int c = cb + cl;
            const float2 f = *(const float2*)&fst_b[(size_t)c * HW + y * W + x0];
#pragma unroll
            for (int r = 0; r < 9; ++r) {
                const float* row = &lds[cl][(ty + r) * LDS_COLS + 2 * tx];
                float w[10];
#pragma unroll
                for (int kk = 0; kk < 5; ++kk) {
                    float2 t2 = *(const float2*)&row[2 * kk];
                    w[2 * kk] = t2.x; w[2 * kk + 1] = t2.y;
                }
#pragma unroll
                for (int dx = 0; dx < 9; ++dx) {
                    acc[r * 9 + dx][0] += f.x * w[dx];
                    acc[r * 9 + dx][1] += f.y * w[dx + 1];
                }
            }
        }
    }
    const float scale = 1.0f / 64.0f;
    float* out_b = out + (size_t)b * NDISP * HW;
#pragma unroll
    for (int d = 0; d < NDISP; ++d) {
        float2 o;
        o.x = acc[d][0] * scale;
        o.y = acc[d][1] * scale;
        *(float2*)&out_b[(size_t)d * HW + y * W + x0] = o;
    }
}

extern "C" void kernel_launch(void* const* d_in, const int* in_sizes, int n_in,
                              void* d_out, int out_size, void* d_ws, size_t ws_size,
                              hipStream_t stream) {
    const float* tenFirst  = (const float*)d_in[0];
    const float* tenSecond = (const float*)d_in[1];
    float* out = (float*)d_out;

    const size_t sp_bytes = (size_t)NB * PH * PW * CC * 2;   // 33.6 MB bf16 padded S
    const size_t fc_bytes = (size_t)NB * HH * WW * CC * 2;   // 31.5 MB bf16 F

    if (ws_size >= sp_bytes + fc_bytes) {
        unsigned short* Sp = (unsigned short*)d_ws;
        unsigned short* Fc = (unsigned short*)((char*)d_ws + sp_bytes);
        prep<<<dim3(6, PH, 8), dim3(64, 4), 0, stream>>>(tenFirst, tenSecond, Fc, Sp);
        corr_mfma_v4<<<11520, 256, 0, stream>>>(Fc, Sp, out);
    } else {
        corr_direct<<<dim3(WW / TILE_X, HH / TILE_Y, NB), dim3(32, 8), 0, stream>>>(
            tenFirst, tenSecond, out);
    }
}